// Round 1
// baseline (254.667 us; speedup 1.0000x reference)
//
#include <hip/hip_runtime.h>

typedef __bf16 bf16x8 __attribute__((ext_vector_type(8)));
typedef float  f32x4  __attribute__((ext_vector_type(4)));
typedef unsigned int u32x4 __attribute__((ext_vector_type(4)));
typedef unsigned short u16x8 __attribute__((ext_vector_type(8)));
typedef unsigned short u16x4 __attribute__((ext_vector_type(4)));
typedef short i16x4 __attribute__((ext_vector_type(4)));

__device__ __forceinline__ unsigned short f2bf(float f) {
    return __builtin_bit_cast(unsigned short, (__bf16)f);
}
__device__ __forceinline__ float bf2f(unsigned short s) {
    return (float)__builtin_bit_cast(__bf16, s);
}
__device__ __forceinline__ bf16x8 as_bf16x8(u32x4 v) {
    return __builtin_bit_cast(bf16x8, v);
}

#define AS1 __attribute__((address_space(1)))
#define AS3 __attribute__((address_space(3)))
__device__ __forceinline__ void gload_lds16(const void* g, void* l) {
    __builtin_amdgcn_global_load_lds((const AS1 void*)g, (AS3 void*)l, 16, 0, 0);
}

// Window-major permutation: m' groups the 4 members of each 2x2 spatial
// window consecutively. n = b*4096 + hh*64 + ww  ->  m' = (b*1024 +
// (hh>>1)*32 + (ww>>1))*4 + (hh&1)*2 + (ww&1).

// ---------------- prep: cast+permute x, 2x2 pool, weight transpose ----------------
__global__ __launch_bounds__(256) void k_prep(
        const float* __restrict__ x,
        const float* __restrict__ h_qkv_w, const float* __restrict__ l_q_w,
        const float* __restrict__ l_kv_w, const float* __restrict__ h_proj_w,
        const float* __restrict__ l_proj_w,
        unsigned short* __restrict__ xb, unsigned short* __restrict__ xpb,
        unsigned short* __restrict__ wcatT, unsigned short* __restrict__ lkvT,
        unsigned short* __restrict__ hprojT, unsigned short* __restrict__ lprojT) {
    int blk = blockIdx.x;
    if (blk < 8192) {
        // cast x -> xb in m'-order (8 elems/thread)
        int t = blk * 256 + threadIdx.x;
        int row = t >> 6, c8 = (t & 63) << 3;
        int b = row >> 12, nn = row & 4095;
        int hh = nn >> 6, ww = nn & 63;
        int mp = (((b << 10) + ((hh >> 1) << 5) + (ww >> 1)) << 2) + ((hh & 1) << 1) + (ww & 1);
        const float* src = x + (size_t)row * 512 + c8;
        f32x4 v0 = *(const f32x4*)src;
        f32x4 v1 = *(const f32x4*)(src + 4);
        u16x8 o = { f2bf(v0[0]), f2bf(v0[1]), f2bf(v0[2]), f2bf(v0[3]),
                    f2bf(v1[0]), f2bf(v1[1]), f2bf(v1[2]), f2bf(v1[3]) };
        *(u16x8*)(xb + (size_t)mp * 512 + c8) = o;
    } else if (blk < 10240) {
        // 2x2 mean pool of x -> xpb [8192,512] (n-order pooled grid)
        int t = (blk - 8192) * 256 + threadIdx.x;
        int r = t >> 6, c8 = (t & 63) << 3;
        int b = r >> 10, hw = r & 1023;
        int h2 = hw >> 5, w2 = hw & 31;
        const float* base = x + ((size_t)(b << 12) + (h2 << 7) + (w2 << 1)) * 512 + c8;
        u16x8 o;
#pragma unroll
        for (int half = 0; half < 2; half++) {
            f32x4 a0 = *(const f32x4*)(base + half * 4);
            f32x4 a1 = *(const f32x4*)(base + 512 + half * 4);
            f32x4 a2 = *(const f32x4*)(base + 64 * 512 + half * 4);
            f32x4 a3 = *(const f32x4*)(base + 65 * 512 + half * 4);
            f32x4 m = (a0 + a1 + a2 + a3) * 0.25f;
#pragma unroll
            for (int j = 0; j < 4; j++) o[half * 4 + j] = f2bf(m[j]);
        }
        *(u16x8*)(xpb + (size_t)r * 512 + c8) = o;
    } else {
        // weights -> B^T bf16
        int i = (blk - 10240) * 256 + threadIdx.x;
        if (i < 262144) {
            int n = i >> 9, k = i & 511;
            float v = (n < 256) ? h_qkv_w[k * 256 + n] : l_q_w[k * 256 + (n - 256)];
            wcatT[i] = f2bf(v);
        } else if (i < 524288) {
            int j = i - 262144; int n = j >> 9, k = j & 511;
            lkvT[j] = f2bf(l_kv_w[k * 512 + n]);
        } else if (i < 589824) {
            int j = i - 524288; int n = j >> 8, k = j & 255;
            hprojT[j] = f2bf(h_proj_w[k * 256 + n]);
        } else {
            int j = i - 589824; int n = j >> 8, k = j & 255;
            lprojT[j] = f2bf(l_proj_w[k * 256 + n]);
        }
    }
}

// ---------------- shared GEMM core: 128x128 tile, BK=32 (m97 structure) ----------------
__device__ __forceinline__ void mm_core(
        const unsigned short* __restrict__ A, const unsigned short* __restrict__ Bt,
        size_t row0, int col0, int K,
        unsigned short* As, unsigned short* Bs, f32x4 (&acc)[4][4]) {
    const int tid = threadIdx.x;
    const int wave = tid >> 6, lane = tid & 63;
    const int m16 = lane & 15, quad = lane >> 4;
    const int wr = wave >> 1, wc = wave & 1;
    const int srow = lane >> 2;
    const int scol = (lane & 3) * 8;
    const unsigned short* Ap0 = A + (row0 + wave * 32 + srow) * (size_t)K + scol;
    const unsigned short* Ap1 = Ap0 + (size_t)16 * K;
    const unsigned short* Bp0 = Bt + (size_t)(col0 + wave * 32 + srow) * K + scol;
    const unsigned short* Bp1 = Bp0 + (size_t)16 * K;
    unsigned short* Al0 = As + wave * 1024;
    unsigned short* Al1 = As + wave * 1024 + 512;
    unsigned short* Bl0 = Bs + wave * 1024;
    unsigned short* Bl1 = Bs + wave * 1024 + 512;

    for (int k0 = 0; k0 < K; k0 += 32) {
        __syncthreads();
        gload_lds16(Ap0 + k0, Al0);
        gload_lds16(Ap1 + k0, Al1);
        gload_lds16(Bp0 + k0, Bl0);
        gload_lds16(Bp1 + k0, Bl1);
        __syncthreads();
        bf16x8 af[4], bfr[4];
#pragma unroll
        for (int mi = 0; mi < 4; mi++)
            af[mi] = as_bf16x8(*(const u32x4*)(As + (wr * 64 + mi * 16 + m16) * 32 + quad * 8));
#pragma unroll
        for (int ni = 0; ni < 4; ni++)
            bfr[ni] = as_bf16x8(*(const u32x4*)(Bs + (wc * 64 + ni * 16 + m16) * 32 + quad * 8));
#pragma unroll
        for (int mi = 0; mi < 4; mi++)
#pragma unroll
            for (int ni = 0; ni < 4; ni++)
                acc[mi][ni] = __builtin_amdgcn_mfma_f32_16x16x32_bf16(af[mi], bfr[ni], acc[mi][ni], 0, 0, 0);
    }
}

// ---------------- launch 2: gemm1 (x@[hqkv|lq] + fused hifi) and kv-gemm (+fused V^T) ----------------
__global__ __launch_bounds__(256, 2) void k_mm512(
        const unsigned short* __restrict__ xb, const unsigned short* __restrict__ xpb,
        const unsigned short* __restrict__ wcatT, const unsigned short* __restrict__ lkvT,
        unsigned short* __restrict__ dbuf, unsigned short* __restrict__ qbuf,
        unsigned short* __restrict__ kbuf, unsigned short* __restrict__ vT) {
    __shared__ __align__(16) unsigned short As[128 * 32];
    __shared__ __align__(16) unsigned short Bs[128 * 32];
    const int flat = blockIdx.x;
    const bool isg1 = flat < 1024;
    const unsigned short* A;
    const unsigned short* Bt;
    size_t row0; int col0;
    if (isg1) { A = xb;  Bt = wcatT; row0 = (size_t)(flat >> 2) * 128; col0 = (flat & 3) * 128; }
    else { int f = flat - 1024; A = xpb; Bt = lkvT; row0 = (size_t)(f >> 2) * 128; col0 = (f & 3) * 128; }

    f32x4 acc[4][4] = {};
    mm_core(A, Bt, row0, col0, 512, As, Bs, acc);

    const int tid = threadIdx.x;
    const int wave = tid >> 6, lane = tid & 63;
    const int m16 = lane & 15, quad = lane >> 4;
    const int wr = wave >> 1, wc = wave & 1;

    if (isg1) {
        if (col0 < 256) {
            // hifi: lane's 4 rows are one 2x2 window (m'-order) -> dbuf = mean - val
#pragma unroll
            for (int mi = 0; mi < 4; mi++)
#pragma unroll
                for (int ni = 0; ni < 4; ni++) {
                    const int col = col0 + wc * 64 + ni * 16 + m16;
                    const size_t mb = row0 + wr * 64 + mi * 16 + quad * 4;
                    float v0 = acc[mi][ni][0], v1 = acc[mi][ni][1];
                    float v2 = acc[mi][ni][2], v3 = acc[mi][ni][3];
                    float m = 0.25f * ((v0 + v1) + (v2 + v3));
                    dbuf[(mb + 0) * 256 + col] = f2bf(m - v0);
                    dbuf[(mb + 1) * 256 + col] = f2bf(m - v1);
                    dbuf[(mb + 2) * 256 + col] = f2bf(m - v2);
                    dbuf[(mb + 3) * 256 + col] = f2bf(m - v3);
                }
        } else {
            // Q: fold softmax scale (0.125) and log2(e) into Q so attn uses exp2 directly
#pragma unroll
            for (int mi = 0; mi < 4; mi++)
#pragma unroll
                for (int ni = 0; ni < 4; ni++) {
                    const int col = col0 - 256 + wc * 64 + ni * 16 + m16;
                    const size_t mb = row0 + wr * 64 + mi * 16 + quad * 4;
#pragma unroll
                    for (int r = 0; r < 4; r++)
                        qbuf[(mb + r) * 256 + col] = f2bf(acc[mi][ni][r] * 0.18033688f);
                }
        }
    } else {
        if (col0 < 256) {
#pragma unroll
            for (int mi = 0; mi < 4; mi++)
#pragma unroll
                for (int ni = 0; ni < 4; ni++) {
                    const int col = col0 + wc * 64 + ni * 16 + m16;
                    const size_t row = row0 + wr * 64 + mi * 16 + quad * 4;
#pragma unroll
                    for (int r = 0; r < 4; r++)
                        kbuf[(row + r) * 256 + col] = f2bf(acc[mi][ni][r]);
                }
        } else {
            // V stored transposed: vT[(b*4+h)*64 + d][kv], lane's 4 rows = 4 consecutive kv
#pragma unroll
            for (int mi = 0; mi < 4; mi++)
#pragma unroll
                for (int ni = 0; ni < 4; ni++) {
                    const int d = col0 - 256 + wc * 64 + ni * 16 + m16;
                    const int hh = d >> 6, dd = d & 63;
                    const size_t kvg = row0 + wr * 64 + mi * 16 + quad * 4;
                    const int b = (int)(kvg >> 10), kv = (int)(kvg & 1023);
                    u16x4 pk = { f2bf(acc[mi][ni][0]), f2bf(acc[mi][ni][1]),
                                 f2bf(acc[mi][ni][2]), f2bf(acc[mi][ni][3]) };
                    *(u16x4*)(vT + (((size_t)(b * 4 + hh) * 64 + dd) << 10) + kv) = pk;
                }
        }
    }
}

// ---------------- launch 4: both projection GEMMs, un-permuting epilogue ----------------
__global__ __launch_bounds__(256, 2) void k_mmproj(
        const unsigned short* __restrict__ dbuf, const unsigned short* __restrict__ aout,
        const unsigned short* __restrict__ hprojT, const unsigned short* __restrict__ lprojT,
        const float* __restrict__ h_proj_b, const float* __restrict__ l_proj_b,
        float* __restrict__ out) {
    __shared__ __align__(16) unsigned short As[128 * 32];
    __shared__ __align__(16) unsigned short Bs[128 * 32];
    const int flat = blockIdx.x;               // 0..1023
    const bool hi = flat < 512;
    const int f = flat & 511;
    const unsigned short* A  = hi ? dbuf : aout;
    const unsigned short* Bt = hi ? hprojT : lprojT;
    const float* bias = hi ? h_proj_b : l_proj_b;
    const int coloff = hi ? 0 : 256;
    const size_t row0 = (size_t)(f >> 1) * 128;
    const int col0 = (f & 1) * 128;

    f32x4 acc[4][4] = {};
    mm_core(A, Bt, row0, col0, 256, As, Bs, acc);

    const int tid = threadIdx.x;
    const int wave = tid >> 6, lane = tid & 63;
    const int m16 = lane & 15, quad = lane >> 4;
    const int wr = wave >> 1, wc = wave & 1;

#pragma unroll
    for (int mi = 0; mi < 4; mi++)
#pragma unroll
        for (int ni = 0; ni < 4; ni++) {
            const int col = col0 + wc * 64 + ni * 16 + m16;
            const float bv = bias[col];
            const size_t mb = row0 + wr * 64 + mi * 16 + quad * 4;
            const int widx = (int)(mb >> 2);
            const int b = widx >> 10, rem = widx & 1023;
            const int h2 = rem >> 5, w2 = rem & 31;
            const size_t nb = ((size_t)b << 12) + (h2 << 7) + (w2 << 1);
            float* op = out + nb * 512 + coloff + col;
            op[0]            = acc[mi][ni][0] + bv;
            op[512]          = acc[mi][ni][1] + bv;
            op[64 * 512]     = acc[mi][ni][2] + bv;
            op[65 * 512]     = acc[mi][ni][3] + bv;
        }
}

// ---------------- fused lo-fi attention: 8 waves x 32 q rows, no P round-trip ----------------
// S^T = K Q^T (16x16x32) leaves P[q=m16][kv=quad*4+r] in registers -- exactly the
// A-fragment layout of v_mfma_f32_16x16x16_bf16. PV consumes P directly from regs;
// V^T B-frags are b64 LDS reads. No Pl buffer, LDS = 72 KB (2 blocks/CU).
// 512 threads/block: same grid (512 blocks) and same per-block staging traffic as the
// 256-thread version, but 16 waves/CU resident (4/SIMD) instead of 8 -- the prior
// version was occupancy/latency-bound (Occupancy 17%, Mfma 37%, VALU 52%).
// Q arrives pre-scaled by 0.125*log2(e), so P = exp2(st) directly.
__global__ __launch_bounds__(512, 4) void k_attn(
        const unsigned short* __restrict__ qbuf,  // [32768,256] m'-order, pre-scaled
        const unsigned short* __restrict__ kbuf,  // [8192,256]
        const unsigned short* __restrict__ vT,    // [32][64][1024]
        unsigned short* __restrict__ aout) {      // [32768,256] m'-order
    __shared__ __align__(16) unsigned short Kb[2][64 * 72];   // [kv][d], pad 72
    __shared__ __align__(16) unsigned short Vb[2][64 * 72];   // [d][kv], pad 72
    const int tid = threadIdx.x;
    const int wave = tid >> 6, lane = tid & 63;
    const int m16 = lane & 15, quad = lane >> 4;
    const int qtile = blockIdx.x, bh = blockIdx.y;
    const int b = bh >> 2, h = bh & 3;

    // Q: 32 rows/wave
    bf16x8 qf[2][2];
    const size_t qrow0 = (size_t)b * 4096 + qtile * 256 + wave * 32;
#pragma unroll
    for (int qh = 0; qh < 2; qh++) {
        const unsigned short* qp = qbuf + (qrow0 + qh * 16 + m16) * 256 + h * 64 + quad * 8;
        qf[qh][0] = as_bf16x8(*(const u32x4*)qp);
        qf[qh][1] = as_bf16x8(*(const u32x4*)(qp + 32));
    }

    f32x4 o[2][4] = {};
    float lp[2] = {0.f, 0.f};

    // staging: threads 0..255 stage K (2 rows x 16B), threads 256..511 stage V
    const int sid = tid & 255;
    const int sr = sid >> 3;       // 0..31
    const int sc = sid & 7;        // 16B chunk
    const bool stV = tid >= 256;   // wave-uniform
    const unsigned short* kg = kbuf + ((size_t)b * 1024) * 256 + h * 64 + sc * 8;
    const unsigned short* vg = vT + ((size_t)bh * 64) * 1024 + sc * 8;

    u32x4 s0, s1;
    if (!stV) {
        s0 = *(const u32x4*)(kg + (size_t)sr * 256);
        s1 = *(const u32x4*)(kg + (size_t)(sr + 32) * 256);
        *(u32x4*)&Kb[0][sr * 72 + sc * 8] = s0;
        *(u32x4*)&Kb[0][(sr + 32) * 72 + sc * 8] = s1;
    } else {
        s0 = *(const u32x4*)(vg + (size_t)sr * 1024);
        s1 = *(const u32x4*)(vg + (size_t)(sr + 32) * 1024);
        *(u32x4*)&Vb[0][sr * 72 + sc * 8] = s0;
        *(u32x4*)&Vb[0][(sr + 32) * 72 + sc * 8] = s1;
    }

    for (int it = 0; it < 16; ++it) {
        const int cur = it & 1, nxt = cur ^ 1;
        __syncthreads();
        if (it + 1 < 16) {
            const size_t kvb = (size_t)(it + 1) * 64;
            if (!stV) {
                s0 = *(const u32x4*)(kg + (kvb + sr) * 256);
                s1 = *(const u32x4*)(kg + (kvb + sr + 32) * 256);
            } else {
                s0 = *(const u32x4*)(vg + kvb + (size_t)sr * 1024);
                s1 = *(const u32x4*)(vg + kvb + (size_t)(sr + 32) * 1024);
            }
        }

#pragma unroll
        for (int mt = 0; mt < 4; mt++) {
            // S^T = K Q^T : C col = q = m16, row = kv = mt*16 + quad*4 + r
            const unsigned short* kp = &Kb[cur][(mt * 16 + m16) * 72 + quad * 8];
            const bf16x8 kf0 = as_bf16x8(*(const u32x4*)kp);
            const bf16x8 kf1 = as_bf16x8(*(const u32x4*)(kp + 32));
            f32x4 st[2];
#pragma unroll
            for (int qh = 0; qh < 2; qh++) {
                f32x4 z = {};
                z = __builtin_amdgcn_mfma_f32_16x16x32_bf16(kf0, qf[qh][0], z, 0, 0, 0);
                st[qh] = __builtin_amdgcn_mfma_f32_16x16x32_bf16(kf1, qf[qh][1], z, 0, 0, 0);
            }
            // P = exp2(S') (scale folded into Q); packed P is directly the K=16 MFMA A-frag
            i16x4 pa[2];
#pragma unroll
            for (int qh = 0; qh < 2; qh++) {
                float p0 = __builtin_exp2f(st[qh][0]);
                float p1 = __builtin_exp2f(st[qh][1]);
                float p2 = __builtin_exp2f(st[qh][2]);
                float p3 = __builtin_exp2f(st[qh][3]);
                lp[qh] += (p0 + p1) + (p2 + p3);
                u16x4 pk = { f2bf(p0), f2bf(p1), f2bf(p2), f2bf(p3) };
                pa[qh] = __builtin_bit_cast(i16x4, pk);
            }
            // O += P_chunk V_chunk  (K=16 MFMA, B-frag = V^T[d][mt*16 + quad*4 + j])
#pragma unroll
            for (int nt = 0; nt < 4; nt++) {
                const i16x4 vb = *(const i16x4*)&Vb[cur][(nt * 16 + m16) * 72 + mt * 16 + quad * 4];
#pragma unroll
                for (int qh = 0; qh < 2; qh++)
                    o[qh][nt] = __builtin_amdgcn_mfma_f32_16x16x16bf16_1k(pa[qh], vb, o[qh][nt], 0, 0, 0);
            }
        }

        if (it + 1 < 16) {
            if (!stV) {
                *(u32x4*)&Kb[nxt][sr * 72 + sc * 8] = s0;
                *(u32x4*)&Kb[nxt][(sr + 32) * 72 + sc * 8] = s1;
            } else {
                *(u32x4*)&Vb[nxt][sr * 72 + sc * 8] = s0;
                *(u32x4*)&Vb[nxt][(sr + 32) * 72 + sc * 8] = s1;
            }
        }
    }

#pragma unroll
    for (int qh = 0; qh < 2; qh++) {
        float l = lp[qh];
        l += __shfl_xor(l, 16);
        l += __shfl_xor(l, 32);
        f32x4 linv;
#pragma unroll
        for (int r = 0; r < 4; r++)
            linv[r] = __builtin_amdgcn_rcpf(__shfl(l, quad * 4 + r));
#pragma unroll
        for (int nt = 0; nt < 4; nt++)
#pragma unroll
            for (int r = 0; r < 4; r++)
                aout[(qrow0 + qh * 16 + quad * 4 + r) * 256 + h * 64 + nt * 16 + m16] =
                    f2bf(o[qh][nt][r] * linv[r]);
    }
}

// ---------------- launcher ----------------

extern "C" void kernel_launch(void* const* d_in, const int* in_sizes, int n_in,
                              void* d_out, int out_size, void* d_ws, size_t ws_size,
                              hipStream_t stream) {
    (void)in_sizes; (void)n_in; (void)out_size; (void)ws_size;
    const float* x        = (const float*)d_in[0];
    const float* l_q_w    = (const float*)d_in[2];
    const float* l_kv_w   = (const float*)d_in[3];
    const float* l_proj_w = (const float*)d_in[4];
    const float* l_proj_b = (const float*)d_in[5];
    const float* h_qkv_w  = (const float*)d_in[6];
    const float* h_proj_w = (const float*)d_in[7];
    const float* h_proj_b = (const float*)d_in[8];
    float* out = (float*)d_out;

    char* ws = (char*)d_ws;
    unsigned short* xb     = (unsigned short*)(ws);             // 33.5MB, dead after mm512
    unsigned short* aout   = (unsigned short*)(ws);             // 16.8MB, overlays xb
    unsigned short* dbuf   = (unsigned short*)(ws + 33554432);  // 16.8MB
    unsigned short* qbuf   = (unsigned short*)(ws + 50331648);  // 16.8MB
    unsigned short* kbuf   = (unsigned short*)(ws + 67108864);  // 4.2MB
    unsigned short* vT     = (unsigned short*)(ws + 71303168);  // 4.2MB
    unsigned short* xpb    = (unsigned short*)(ws + 75497472);  // 8.4MB
    unsigned short* wcatT  = (unsigned short*)(ws + 83886080);
    unsigned short* lkvT   = (unsigned short*)(ws + 84410368);
    unsigned short* hprojT = (unsigned short*)(ws + 84934656);
    unsigned short* lprojT = (unsigned short*)(ws + 85065728);
    // total ws requirement: 85,196,800 B (same as prior rounds)

    k_prep<<<12800, 256, 0, stream>>>(x, h_qkv_w, l_q_w, l_kv_w, h_proj_w, l_proj_w,
                                      xb, xpb, wcatT, lkvT, hprojT, lprojT);
    // gemm1 (1024 blocks) + kv-gemm (256 blocks), fused hifi / V^T epilogues
    k_mm512<<<1280, 256, 0, stream>>>(xb, xpb, wcatT, lkvT, dbuf, qbuf, kbuf, vT);
    // attention (aout overlays xb -- xb dead after mm512); 512 thr, 2 blk/CU, 4 waves/SIMD
    k_attn<<<dim3(16, 32), 512, 0, stream>>>(qbuf, kbuf, vT, aout);
    // both projections + bias + un-permute into out
    k_mmproj<<<1024, 256, 0, stream>>>(dbuf, aout, hprojT, lprojT, h_proj_b, l_proj_b, out);
}